// Round 11
// baseline (216.639 us; speedup 1.0000x reference)
//
#include <hip/hip_runtime.h>
#include <hip/hip_bf16.h>
#include <cstdint>

#define BATCH 32
#define NKEY 2048
#define DIM 256
#define NHEAD 8
#define SEEDS 32
#define DHEAD 32
#define SCALE 0.0625f
#define NCHUNK 16
#define KCH 128           // keys per attn block
#define KT 32             // keys per inner step
#define PART_BYTES 17408  // 8192 bf16 numer (16384B) + 256 f32 denom (1024B)

typedef unsigned short u16;
typedef __attribute__((ext_vector_type(8))) short s16x8;
typedef __attribute__((ext_vector_type(8))) unsigned short u16x8;
typedef __attribute__((ext_vector_type(4))) unsigned short u16x4;
typedef __attribute__((ext_vector_type(4))) float f32x4;

__device__ __forceinline__ u16 f2bf(float f) {
    unsigned u = __float_as_uint(f);
    u += 0x7FFFu + ((u >> 16) & 1u);
    return (u16)(u >> 16);
}
__device__ __forceinline__ float bf2f(u16 h) {
    return __uint_as_float(((unsigned)h) << 16);
}
// lengths may arrive as int32 or raw int64; lengths>=1 so int64 layout has lens[1]==0
__device__ __forceinline__ int get_len(const int* lens, int b) {
    return (lens[1] == 0) ? lens[2 * b] : lens[b];
}
__device__ __forceinline__ u16x8 cvt8(const float* p) {
    f32x4 a = *(const f32x4*)p;
    f32x4 b = *(const f32x4*)(p + 4);
    u16x8 r;
    r[0] = f2bf(a[0]); r[1] = f2bf(a[1]); r[2] = f2bf(a[2]); r[3] = f2bf(a[3]);
    r[4] = f2bf(b[0]); r[5] = f2bf(b[1]); r[6] = f2bf(b[2]); r[7] = f2bf(b[3]);
    return r;
}
__device__ __forceinline__ u16x4 cvt4(f32x4 a) {
    u16x4 r;
    r[0] = f2bf(a[0]); r[1] = f2bf(a[1]); r[2] = f2bf(a[2]); r[3] = f2bf(a[3]);
    return r;
}
// async global->LDS, 16B per lane; lds base must be wave-uniform (dest = base + lane*16)
__device__ __forceinline__ void glds16(const u16* g, u16* l) {
    __builtin_amdgcn_global_load_lds(
        (const __attribute__((address_space(1))) unsigned int*)g,
        (__attribute__((address_space(3))) unsigned int*)l, 16, 0, 0);
}

// ---------------- Kernel 0: W fp32->bf16 (tiny) + fused qproj ----------------
// blocks 0..63: convert Wk|Wv (16384 groups of 8); blocks 64..95: qproj seed s
__global__ __launch_bounds__(256) void wcvt_kernel(const float* __restrict__ Wk,
                                                   const float* __restrict__ Wv,
                                                   const float* __restrict__ S,
                                                   const float* __restrict__ Wq,
                                                   u16* __restrict__ wb,
                                                   float* __restrict__ qf) {
    if (blockIdx.x < 64) {
        size_t gw = (size_t)blockIdx.x * 256 + threadIdx.x;  // 0..16383
        const float* src = (gw < 8192) ? (Wk + gw * 8) : (Wv + (gw - 8192) * 8);
        *(u16x8*)(wb + gw * 8) = cvt8(src);
        return;
    }
    // fused qproj: Q = S @ Wq^T, one block per seed
    int s = blockIdx.x - 64;
    int e = threadIdx.x;
    __shared__ float srow[DIM];
    srow[e] = S[s * DIM + e];
    __syncthreads();
    const float* wr = Wq + (size_t)e * DIM;
    float acc = 0.f;
#pragma unroll 4
    for (int d = 0; d < DIM; d += 4) {
        f32x4 w = *(const f32x4*)(wr + d);
        acc += srow[d] * w[0] + srow[d + 1] * w[1] + srow[d + 2] * w[2] + srow[d + 3] * w[3];
    }
    qf[s * DIM + e] = acc;
}

// ---------------- Kernel 2: K,V^T = x @ wb^T  (fp32 A reg-staged, 2-phase dbuf) ----------------
#define BM 128
#define BN 128
#define BK 32
#define NSTEP (DIM / BK)

__global__ __launch_bounds__(256) void kv_gemm_kernel(const float* __restrict__ x,
                                                      const u16* __restrict__ wb,
                                                      u16* __restrict__ kg,
                                                      u16* __restrict__ vt) {
    __shared__ u16 Alds[2][BM * BK];  // 2 x 8 KB
    __shared__ u16 Blds[2][BM * BK];  // 2 x 8 KB (global_load_lds dest, linear)
    int bid = blockIdx.x;
    int swz = (bid & 7) * 256 + (bid >> 3);
    int nb = swz & 3;    // output col block (0..3)
    int mb = swz >> 2;   // row block (0..511)
    const u16* bsrc = wb + (size_t)nb * BN * DIM;

    int tid = threadIdx.x;
    int lane = tid & 63;
    int wid = tid >> 6;
    int wr = wid >> 1, wc = wid & 1;
    int k8 = (lane >> 4) * 8;   // k-offset (elems) for this lane group (bijection k=8g+j)
    int fr = lane & 15;         // fragment row/col index

    // A staging (fp32 -> reg -> cvt -> ds_write): f32x4 id f = w*256+tid;
    // row = w*32 + (tid>>3), col4 = tid&7  -> fully coalesced 4KB per load inst
    int ar = tid >> 3;          // row within 32-row group
    int ac = (tid & 7) * 4;     // elem col
    const float* ax = x + ((size_t)mb * BM + ar) * DIM + ac;

    // B staging (bf16 glds16): wave wid covers rows [wid*32,+32); lane l -> +(l>>2), col (l&3)*8
    int srow = wid * 32 + (lane >> 2);
    int scol = (lane & 3) * 8;
    const u16* gb0 = bsrc + (size_t)srow * DIM + scol;

    f32x4 acc[4][4];
#pragma unroll
    for (int m = 0; m < 4; m++)
#pragma unroll
        for (int n = 0; n < 4; n++) acc[m][n] = (f32x4){0.f, 0.f, 0.f, 0.f};

    // prologue: stage step 0 into buffer 0
    f32x4 areg[4];
#pragma unroll
    for (int w = 0; w < 4; w++)
        areg[w] = *(const f32x4*)(ax + (size_t)w * 32 * DIM);
    glds16(gb0,            &Blds[0][(wid * 32) * BK]);
    glds16(gb0 + 16 * DIM, &Blds[0][(wid * 32 + 16) * BK]);
#pragma unroll
    for (int w = 0; w < 4; w++)
        *(u16x4*)&Alds[0][(w * 32 + ar) * BK + ac] = cvt4(areg[w]);
    __syncthreads();  // drains vmcnt+lgkm

    for (int t = 0; t < NSTEP; t++) {
        int cur = t & 1;
        if (t + 1 < NSTEP) {
            // issue next-step A loads (regs) + B glds16 BEFORE compute
#pragma unroll
            for (int w = 0; w < 4; w++)
                areg[w] = *(const f32x4*)(ax + (size_t)w * 32 * DIM + (t + 1) * BK);
            const u16* gb = gb0 + (t + 1) * BK;
            glds16(gb,            &Blds[cur ^ 1][(wid * 32) * BK]);
            glds16(gb + 16 * DIM, &Blds[cur ^ 1][(wid * 32 + 16) * BK]);
        }
        s16x8 af[4], bfg[4];
#pragma unroll
        for (int m = 0; m < 4; m++)
            af[m] = *(const s16x8*)&Alds[cur][(wr * 64 + m * 16 + fr) * BK + k8];
#pragma unroll
        for (int n = 0; n < 4; n++)
            bfg[n] = *(const s16x8*)&Blds[cur][(wc * 64 + n * 16 + fr) * BK + k8];
#pragma unroll
        for (int m = 0; m < 4; m++)
#pragma unroll
            for (int n = 0; n < 4; n++)
                acc[m][n] = __builtin_amdgcn_mfma_f32_16x16x32_bf16(af[m], bfg[n], acc[m][n], 0, 0, 0);
        if (t + 1 < NSTEP) {
            // cvt + LDS-write A(t+1) after MFMA (load latency hidden under compute)
#pragma unroll
            for (int w = 0; w < 4; w++)
                *(u16x4*)&Alds[cur ^ 1][(w * 32 + ar) * BK + ac] = cvt4(areg[w]);
        }
        __syncthreads();  // cur buffers fully consumed; next buffers staged
    }

    // C layout: row (M) = gmbase + m*16 + q, col (N) = gnbase + n*16
    int gmbase = mb * BM + wr * 64 + (lane >> 4) * 4;
    int gnbase = nb * BN + wc * 64 + fr;
#pragma unroll
    for (int m = 0; m < 4; m++) {
        int r0 = gmbase + m * 16;          // 4-aligned global row (b*2048+key)
#pragma unroll
        for (int n = 0; n < 4; n++) {
            int gc = gnbase + n * 16;
            if (gc < 256) {
                // K half: kg[row][col ^ ((row&7)<<3)]  (bank pre-swizzle for attn LDS reads)
#pragma unroll
                for (int q = 0; q < 4; q++) {
                    int r = r0 + q;
                    kg[(size_t)r * 256 + (gc ^ ((r & 7) << 3))] = f2bf(acc[m][n][q]);
                }
            } else {
                // V half: vt[b][dh][key], 4 consecutive keys -> one 8B store
                int dh = gc - 256;
                int bidx = r0 >> 11, key = r0 & 2047;
                u16x4 v = {f2bf(acc[m][n][0]), f2bf(acc[m][n][1]),
                           f2bf(acc[m][n][2]), f2bf(acc[m][n][3])};
                *(u16x4*)&vt[((size_t)bidx * 256 + dh) * NKEY + key] = v;
            }
        }
    }
}

// ---------------- Kernel 3: MFMA attention (partials, 2-phase dbuf) ----------------
// block = 512 threads = 8 waves, wave w = head w; processes KCH=128 keys of batch b.
__global__ __launch_bounds__(512) void attn_kernel(const u16* __restrict__ kg,
                                                   const u16* __restrict__ vt,
                                                   const float* __restrict__ qf,
                                                   const int* __restrict__ lens,
                                                   char* __restrict__ partials) {
    int b = blockIdx.y, chunk = blockIdx.x;
    int len = get_len(lens, b);
    int n0 = chunk * KCH;
    int n1 = min(n0 + KCH, len);
    int tid = threadIdx.x;
    int lane = tid & 63;
    int h = tid >> 6;          // wave = head
    int fr = lane & 15;
    int g = lane >> 4;         // 0..3
    int k8 = g * 8;

    __shared__ u16 Klds[2][KT * 256];     // 2 x 16 KB  [key][dh^((key&7)<<3)]
    __shared__ u16 VTlds[2][256 * KT];    // 2 x 16 KB  [dh][key]
    __shared__ u16 Plds[NHEAD][32][32];   // 16 KB  [h][seed][key slot-XOR seed&3]

    // Q B-fragments: lane fr=seed holds Q[seed][h*32 + k8 + j]
    s16x8 qb[2];
    qb[0] = (s16x8)cvt8(qf + (size_t)(fr) * DIM + h * DHEAD + k8);
    qb[1] = (s16x8)cvt8(qf + (size_t)(16 + fr) * DIM + h * DHEAD + k8);

    f32x4 accp[2][2];          // PV accum: [seed half][dh half]
#pragma unroll
    for (int i = 0; i < 2; i++)
#pragma unroll
        for (int j = 0; j < 2; j++) accp[i][j] = (f32x4){0.f, 0.f, 0.f, 0.f};
    float dsum[2] = {0.f, 0.f};

    int nk = n1 - n0;
    int nsteps = (nk > 0) ? ((nk + KT - 1) / KT) : 0;  // block-uniform

    // staging addresses (wave h stages K rows h*4..h*4+3, VT rows h*32..h*32+31)
    const u16* gk0 = kg + ((size_t)(b * NKEY + n0 + h * 4) + (lane >> 5)) * 256 + (lane & 31) * 8;
    const u16* gv0 = vt + ((size_t)b * 256 + h * 32 + (lane >> 2)) * NKEY + n0 + (lane & 3) * 8;

    if (nsteps > 0) {
        glds16(gk0,             &Klds[0][(h * 4) * 256]);
        glds16(gk0 + 2 * 256,   &Klds[0][(h * 4 + 2) * 256]);
        glds16(gv0,             &VTlds[0][(h * 32) * KT]);
        glds16(gv0 + 16 * NKEY, &VTlds[0][(h * 32 + 16) * KT]);
        __syncthreads();
    }

    for (int t = 0; t < nsteps; t++) {
        int cur = t & 1;
        if (t + 1 < nsteps) {
            const u16* gk = gk0 + (size_t)(t + 1) * KT * 256;
            const u16* gv = gv0 + (t + 1) * KT;
            glds16(gk,             &Klds[cur ^ 1][(h * 4) * 256]);
            glds16(gk + 2 * 256,   &Klds[cur ^ 1][(h * 4 + 2) * 256]);
            glds16(gv,             &VTlds[cur ^ 1][(h * 32) * KT]);
            glds16(gv + 16 * NKEY, &VTlds[cur ^ 1][(h * 32 + 16) * KT]);
        }

        int rem = nk - t * KT;  // valid keys in this tile (may exceed KT; mask below)

        // ---- QK^T: C[key][seed] = K @ Q^T
        s16x8 ka[2];
#pragma unroll
        for (int m = 0; m < 2; m++)
            ka[m] = *(const s16x8*)&Klds[cur][(m * 16 + fr) * 256 + (((h * 4 + g) ^ (fr & 7)) << 3)];
        f32x4 sc[2][2];
#pragma unroll
        for (int m = 0; m < 2; m++)
#pragma unroll
            for (int n = 0; n < 2; n++) {
                f32x4 z = (f32x4){0.f, 0.f, 0.f, 0.f};
                sc[m][n] = __builtin_amdgcn_mfma_f32_16x16x32_bf16(ka[m], qb[n], z, 0, 0, 0);
            }

        // ---- exp + mask + denom + P store (per-wave private Plds[h])
#pragma unroll
        for (int m = 0; m < 2; m++) {
            int kbase = m * 16 + g * 4;
            int col = (((kbase >> 3) ^ (fr & 3)) << 3) + (kbase & 7);
#pragma unroll
            for (int n = 0; n < 2; n++) {
                u16x4 pv;
#pragma unroll
                for (int q = 0; q < 4; q++) {
                    float e = (kbase + q < rem) ? __expf(sc[m][n][q] * SCALE) : 0.f;
                    dsum[n] += e;
                    pv[q] = f2bf(e);
                }
                *(u16x4*)&Plds[h][n * 16 + fr][col] = pv;
            }
        }
        // same-wave LDS RAW: compiler inserts lgkmcnt wait

        // ---- PV: numer[seed][dh] += P @ (V^T)^T
        s16x8 pa[2], vb[2];
        int rcol = (g ^ (fr & 3)) << 3;
#pragma unroll
        for (int m = 0; m < 2; m++)
            pa[m] = *(const s16x8*)&Plds[h][m * 16 + fr][rcol];
#pragma unroll
        for (int n = 0; n < 2; n++)
            vb[n] = *(const s16x8*)&VTlds[cur][(h * 32 + n * 16 + fr) * KT + k8];
#pragma unroll
        for (int m = 0; m < 2; m++)
#pragma unroll
            for (int n = 0; n < 2; n++)
                accp[m][n] = __builtin_amdgcn_mfma_f32_16x16x32_bf16(pa[m], vb[n], accp[m][n], 0, 0, 0);
        __syncthreads();  // drains this iter's prefetch; cur buffers fully consumed
    }

    // ---- denom: sum across the 4 lane-groups (keys were split over g and regs)
    dsum[0] += __shfl_xor(dsum[0], 16);
    dsum[0] += __shfl_xor(dsum[0], 32);
    dsum[1] += __shfl_xor(dsum[1], 16);
    dsum[1] += __shfl_xor(dsum[1], 32);

    // ---- write partials: numer layout [seed][256 dh] bf16, denom [h*32+s] f32
    char* pb = partials + ((size_t)b * NCHUNK + chunk) * PART_BYTES;
    u16* pnum = (u16*)pb;
    float* pden = (float*)(pb + 16384);
#pragma unroll
    for (int m = 0; m < 2; m++)
#pragma unroll
        for (int n = 0; n < 2; n++)
#pragma unroll
            for (int q = 0; q < 4; q++)
                pnum[(size_t)(m * 16 + g * 4 + q) * DIM + h * DHEAD + n * 16 + fr] =
                    f2bf(accp[m][n][q]);
    if (lane < 16) {
        pden[h * 32 + fr] = dsum[0];
        pden[h * 32 + 16 + fr] = dsum[1];
    }
}

// ---------------- Kernel 4: reduce partials -> O_pre = Q + numer/denom ----------------
__global__ __launch_bounds__(256) void reduce_kernel(const char* __restrict__ partials,
                                                     const float* __restrict__ qf,
                                                     const int* __restrict__ lens,
                                                     float* __restrict__ opre,
                                                     float* __restrict__ outlen) {
    int b = blockIdx.x;
    int p = threadIdx.x;
    int h = p >> 5, s = p & 31;
    float denom = 0.f;
    float num[DHEAD];
#pragma unroll
    for (int j = 0; j < DHEAD; j++) num[j] = 0.f;
    for (int c = 0; c < NCHUNK; c++) {
        const char* pb = partials + ((size_t)b * NCHUNK + c) * PART_BYTES;
        denom += ((const float*)(pb + 16384))[p];
        const u16* pn = (const u16*)pb;
#pragma unroll
        for (int j = 0; j < DHEAD; j += 8) {
            u16x8 u = *(const u16x8*)&pn[(size_t)s * DIM + h * DHEAD + j];
#pragma unroll
            for (int t = 0; t < 8; t++) num[j + t] += bf2f(u[t]);
        }
    }
    float inv = 1.f / (denom + 1e-15f);
    size_t obase = ((size_t)b * SEEDS + s) * DIM + h * DHEAD;
#pragma unroll
    for (int j = 0; j < DHEAD; j++) {
        opre[obase + j] = qf[s * DIM + h * DHEAD + j] + num[j] * inv;
    }
    if (p == 0) outlen[b] = (float)min(SEEDS, get_len(lens, b));
}

// ---------------- Kernel 5: epilogue  out = (O + relu(O @ Wo^T)) * row_mask ----------------
__global__ __launch_bounds__(256) void epilogue_kernel(const float* __restrict__ opre,
                                                       const float* __restrict__ Wo,
                                                       const int* __restrict__ lens,
                                                       float* __restrict__ out) {
    int s = blockIdx.x, b = blockIdx.y;
    int d = threadIdx.x;
    size_t rbase = ((size_t)b * SEEDS + s) * DIM;
    if (s >= get_len(lens, b)) {
        out[rbase + d] = 0.f;
        return;
    }
    __shared__ float orow[DIM];
    orow[d] = opre[rbase + d];
    __syncthreads();
    const float* wrow = Wo + (size_t)d * DIM;
    float acc = 0.f;
#pragma unroll 4
    for (int e = 0; e < DIM; e += 4) {
        f32x4 w = *(const f32x4*)(wrow + e);
        acc += orow[e] * w[0] + orow[e + 1] * w[1] + orow[e + 2] * w[2] + orow[e + 3] * w[3];
    }
    out[rbase + d] = orow[d] + fmaxf(acc, 0.f);
}

extern "C" void kernel_launch(void* const* d_in, const int* in_sizes, int n_in,
                              void* d_out, int out_size, void* d_ws, size_t ws_size,
                              hipStream_t stream) {
    const float* x  = (const float*)d_in[0];
    const int* lens = (const int*)d_in[1];
    const float* S  = (const float*)d_in[2];
    const float* Wq = (const float*)d_in[3];
    const float* Wk = (const float*)d_in[4];
    const float* Wv = (const float*)d_in[5];
    const float* Wo = (const float*)d_in[6];
    float* out = (float*)d_out;

    char* ws = (char*)d_ws;
    float* qf       = (float*)ws;                         // 32 KB
    float* opre     = (float*)(ws + 0x8000);              // 1 MB
    u16*   wb       = (u16*)  (ws + 0x108000);            // 256 KB bf16 [Wk;Wv]
    char*  partials = (char*) (ws + 0x148000);            // 8.9 MB
    u16*   kg       = (u16*)  (ws + 0x2148000);           // 32 MiB bf16 K (col-swizzled)
    u16*   vt       = (u16*)  (ws + 0x4148000);           // 32 MiB bf16 V^T [b][dh][key]

    wcvt_kernel<<<dim3(96), 256, 0, stream>>>(Wk, Wv, S, Wq, wb, qf);
    kv_gemm_kernel<<<dim3(2048), 256, 0, stream>>>(x, wb, kg, vt);
    attn_kernel<<<dim3(NCHUNK, BATCH), 512, 0, stream>>>(kg, vt, qf, lens, partials);
    reduce_kernel<<<dim3(BATCH), 256, 0, stream>>>(partials, qf, lens, opre,
                                                   out + (size_t)BATCH * SEEDS * DIM);
    epilogue_kernel<<<dim3(SEEDS, BATCH), 256, 0, stream>>>(opre, Wo, lens, out);
}

// Round 15
// 206.308 us; speedup vs baseline: 1.0501x; 1.0501x over previous
//
#include <hip/hip_runtime.h>
#include <hip/hip_bf16.h>
#include <cstdint>

#define BATCH 32
#define NKEY 2048
#define DIM 256
#define NHEAD 8
#define SEEDS 32
#define DHEAD 32
#define SCALE 0.0625f
#define NCHUNK 16
#define KCH 128           // keys per attn block
#define KT 32             // keys per inner step
#define PART_BYTES 17408  // 8192 bf16 numer (16384B) + 256 f32 denom (1024B)

typedef unsigned short u16;
typedef __attribute__((ext_vector_type(8))) short s16x8;
typedef __attribute__((ext_vector_type(8))) unsigned short u16x8;
typedef __attribute__((ext_vector_type(4))) unsigned short u16x4;
typedef __attribute__((ext_vector_type(4))) float f32x4;

__device__ __forceinline__ u16 f2bf(float f) {
    unsigned u = __float_as_uint(f);
    u += 0x7FFFu + ((u >> 16) & 1u);
    return (u16)(u >> 16);
}
__device__ __forceinline__ float bf2f(u16 h) {
    return __uint_as_float(((unsigned)h) << 16);
}
// lengths may arrive as int32 or raw int64; lengths>=1 so int64 layout has lens[1]==0
__device__ __forceinline__ int get_len(const int* lens, int b) {
    return (lens[1] == 0) ? lens[2 * b] : lens[b];
}
__device__ __forceinline__ u16x8 cvt8(const float* p) {
    f32x4 a = *(const f32x4*)p;
    f32x4 b = *(const f32x4*)(p + 4);
    u16x8 r;
    r[0] = f2bf(a[0]); r[1] = f2bf(a[1]); r[2] = f2bf(a[2]); r[3] = f2bf(a[3]);
    r[4] = f2bf(b[0]); r[5] = f2bf(b[1]); r[6] = f2bf(b[2]); r[7] = f2bf(b[3]);
    return r;
}
// async global->LDS, 16B per lane; lds base must be wave-uniform (dest = base + lane*16)
__device__ __forceinline__ void glds16(const u16* g, u16* l) {
    __builtin_amdgcn_global_load_lds(
        (const __attribute__((address_space(1))) unsigned int*)g,
        (__attribute__((address_space(3))) unsigned int*)l, 16, 0, 0);
}

// ---------------- Kernel 0: fp32->bf16 convert (x, Wk|Wv) + fused qproj ----------------
#define XGROUPS 2097152  // 16777216 x-elems / 8
#define WGROUPS 16384    // 131072 w-elems / 8
#define CVTBLK 2048
__global__ __launch_bounds__(256) void cvt_kernel(const float* __restrict__ x,
                                                  const float* __restrict__ Wk,
                                                  const float* __restrict__ Wv,
                                                  const float* __restrict__ S,
                                                  const float* __restrict__ Wq,
                                                  u16* __restrict__ xb,
                                                  u16* __restrict__ wb,
                                                  float* __restrict__ qf) {
    if (blockIdx.x >= CVTBLK) {
        // fused qproj: Q = S @ Wq^T, one block per seed
        int s = blockIdx.x - CVTBLK;
        int e = threadIdx.x;
        __shared__ float srow[DIM];
        srow[e] = S[s * DIM + e];
        __syncthreads();
        const float* wr = Wq + (size_t)e * DIM;
        float acc = 0.f;
#pragma unroll 4
        for (int d = 0; d < DIM; d += 4) {
            f32x4 w = *(const f32x4*)(wr + d);
            acc += srow[d] * w[0] + srow[d + 1] * w[1] + srow[d + 2] * w[2] + srow[d + 3] * w[3];
        }
        qf[s * DIM + e] = acc;
        return;
    }
    size_t g = (size_t)blockIdx.x * 256 + threadIdx.x;
    const size_t stride = (size_t)CVTBLK * 256;
    for (; g < XGROUPS + WGROUPS; g += stride) {
        const float* src;
        u16* dst;
        if (g < XGROUPS) {
            src = x + g * 8;
            dst = xb + g * 8;
        } else {
            size_t gw = g - XGROUPS;
            dst = wb + gw * 8;
            src = (gw < 8192) ? (Wk + gw * 8) : (Wv + (gw - 8192) * 8);
        }
        *(u16x8*)dst = cvt8(src);
    }
}

// ---------------- Kernel 2: K,V^T = xb @ wb^T (bf16 MFMA, BK=64, both-sides XOR swizzle) ----
#define BM 128
#define BN 128
#define BK 64
#define NSTEP (DIM / BK)   // 4

__global__ __launch_bounds__(256) void kv_gemm_kernel(const u16* __restrict__ xb,
                                                      const u16* __restrict__ wb,
                                                      u16* __restrict__ kg,
                                                      u16* __restrict__ vt) {
    __shared__ u16 Alds[2][BM * BK];  // 2 x 16 KB, linear (global_load_lds dest)
    __shared__ u16 Blds[2][BM * BK];  // 2 x 16 KB
    int bid = blockIdx.x;
    int swz = (bid & 7) * 256 + (bid >> 3);
    int nb = swz & 3;    // output col block (0..3)
    int mb = swz >> 2;   // row block (0..511)
    const u16* asrc = xb + (size_t)mb * BM * DIM;
    const u16* bsrc = wb + (size_t)nb * BN * DIM;

    int tid = threadIdx.x;
    int lane = tid & 63;
    int wid = tid >> 6;
    int wr = wid >> 1, wc = wid & 1;
    int g = lane >> 4;          // lane k-group (bijection k=8g+j)
    int k8 = g * 8;
    int fr = lane & 15;         // fragment row/col index
    int f7 = fr & 7;            // row&7 for swizzle

    // staging: per wave, rows [wid*32,+32), 4 insts per matrix per step.
    // lane l -> subrow sr=l>>3 (row&7 == sr), col granule (l&7)*8, PRE-SWIZZLED by row:
    // LDS[row][c] = src[row][c ^ ((row&7)<<3)]  (LDS linear, swizzle on global col)
    int sr = lane >> 3;
    int scol = ((lane & 7) * 8) ^ (sr << 3);
    const u16* ga0 = asrc + (size_t)(wid * 32 + sr) * DIM + scol;
    const u16* gb0 = bsrc + (size_t)(wid * 32 + sr) * DIM + scol;

    f32x4 acc[4][4];
#pragma unroll
    for (int m = 0; m < 4; m++)
#pragma unroll
        for (int n = 0; n < 4; n++) acc[m][n] = (f32x4){0.f, 0.f, 0.f, 0.f};

#define STAGE_KV(buf, t)                                                          \
    {                                                                             \
        _Pragma("unroll") for (int i = 0; i < 4; i++) {                           \
            glds16(ga0 + (size_t)i * 8 * DIM + (t) * BK,                          \
                   &Alds[buf][(wid * 32 + i * 8) * BK]);                          \
            glds16(gb0 + (size_t)i * 8 * DIM + (t) * BK,                          \
                   &Blds[buf][(wid * 32 + i * 8) * BK]);                          \
        }                                                                         \
    }

    STAGE_KV(0, 0);
    __syncthreads();  // vmcnt(0) drain + barrier

    for (int t = 0; t < NSTEP; t++) {
        int cur = t & 1;
        if (t + 1 < NSTEP) STAGE_KV(cur ^ 1, t + 1);  // prefetch before compute
#pragma unroll
        for (int sub = 0; sub < 2; sub++) {
            int csw = sub * 32 + k8;
            s16x8 af[4], bfg[4];
#pragma unroll
            for (int m = 0; m < 4; m++)
                af[m] = *(const s16x8*)&Alds[cur][(wr * 64 + m * 16 + fr) * BK + (csw ^ (f7 << 3))];
#pragma unroll
            for (int n = 0; n < 4; n++)
                bfg[n] = *(const s16x8*)&Blds[cur][(wc * 64 + n * 16 + fr) * BK + (csw ^ (f7 << 3))];
#pragma unroll
            for (int m = 0; m < 4; m++)
#pragma unroll
                for (int n = 0; n < 4; n++)
                    acc[m][n] = __builtin_amdgcn_mfma_f32_16x16x32_bf16(af[m], bfg[n], acc[m][n], 0, 0, 0);
        }
        __syncthreads();  // drains this iter's prefetch; cur buffer fully consumed
    }

    // C layout: row (M) = gmbase + m*16 + q, col (N) = gnbase + n*16
    int gmbase = mb * BM + wr * 64 + (lane >> 4) * 4;
    int gnbase = nb * BN + wc * 64 + fr;
#pragma unroll
    for (int m = 0; m < 4; m++) {
        int r0 = gmbase + m * 16;          // 4-aligned global row (b*2048+key)
#pragma unroll
        for (int n = 0; n < 4; n++) {
            int gc = gnbase + n * 16;
            if (gc < 256) {
                // K half: kg[row][col ^ ((row&7)<<3)]  (bank pre-swizzle for attn LDS reads)
#pragma unroll
                for (int q = 0; q < 4; q++) {
                    int r = r0 + q;
                    kg[(size_t)r * 256 + (gc ^ ((r & 7) << 3))] = f2bf(acc[m][n][q]);
                }
            } else {
                // V half: vt[b][dh][key], 4 consecutive keys -> one 8B store
                int dh = gc - 256;
                int bidx = r0 >> 11, key = r0 & 2047;
                u16x4 v = {f2bf(acc[m][n][0]), f2bf(acc[m][n][1]),
                           f2bf(acc[m][n][2]), f2bf(acc[m][n][3])};
                *(u16x4*)&vt[((size_t)bidx * 256 + dh) * NKEY + key] = v;
            }
        }
    }
}

// ---------------- Kernel 3: MFMA attention (partials, 2-phase dbuf) ----------------
// block = 512 threads = 8 waves, wave w = head w; processes KCH=128 keys of batch b.
__global__ __launch_bounds__(512) void attn_kernel(const u16* __restrict__ kg,
                                                   const u16* __restrict__ vt,
                                                   const float* __restrict__ qf,
                                                   const int* __restrict__ lens,
                                                   char* __restrict__ partials) {
    int b = blockIdx.y, chunk = blockIdx.x;
    int len = get_len(lens, b);
    int n0 = chunk * KCH;
    int n1 = min(n0 + KCH, len);
    int tid = threadIdx.x;
    int lane = tid & 63;
    int h = tid >> 6;          // wave = head
    int fr = lane & 15;
    int g = lane >> 4;         // 0..3
    int k8 = g * 8;

    __shared__ u16 Klds[2][KT * 256];     // 2 x 16 KB  [key][dh^((key&7)<<3)]
    __shared__ u16 VTlds[2][256 * KT];    // 2 x 16 KB  [dh][key]
    __shared__ u16 Plds[NHEAD][32][32];   // 16 KB  [h][seed][key slot-XOR seed&3]

    // Q B-fragments: lane fr=seed holds Q[seed][h*32 + k8 + j]
    s16x8 qb[2];
    qb[0] = (s16x8)cvt8(qf + (size_t)(fr) * DIM + h * DHEAD + k8);
    qb[1] = (s16x8)cvt8(qf + (size_t)(16 + fr) * DIM + h * DHEAD + k8);

    f32x4 accp[2][2];          // PV accum: [seed half][dh half]
#pragma unroll
    for (int i = 0; i < 2; i++)
#pragma unroll
        for (int j = 0; j < 2; j++) accp[i][j] = (f32x4){0.f, 0.f, 0.f, 0.f};
    float dsum[2] = {0.f, 0.f};

    int nk = n1 - n0;
    int nsteps = (nk > 0) ? ((nk + KT - 1) / KT) : 0;  // block-uniform

    // staging addresses (wave h stages K rows h*4..h*4+3, VT rows h*32..h*32+31)
    const u16* gk0 = kg + ((size_t)(b * NKEY + n0 + h * 4) + (lane >> 5)) * 256 + (lane & 31) * 8;
    const u16* gv0 = vt + ((size_t)b * 256 + h * 32 + (lane >> 2)) * NKEY + n0 + (lane & 3) * 8;

    if (nsteps > 0) {
        glds16(gk0,             &Klds[0][(h * 4) * 256]);
        glds16(gk0 + 2 * 256,   &Klds[0][(h * 4 + 2) * 256]);
        glds16(gv0,             &VTlds[0][(h * 32) * KT]);
        glds16(gv0 + 16 * NKEY, &VTlds[0][(h * 32 + 16) * KT]);
        __syncthreads();
    }

    for (int t = 0; t < nsteps; t++) {
        int cur = t & 1;
        if (t + 1 < nsteps) {
            const u16* gk = gk0 + (size_t)(t + 1) * KT * 256;
            const u16* gv = gv0 + (t + 1) * KT;
            glds16(gk,             &Klds[cur ^ 1][(h * 4) * 256]);
            glds16(gk + 2 * 256,   &Klds[cur ^ 1][(h * 4 + 2) * 256]);
            glds16(gv,             &VTlds[cur ^ 1][(h * 32) * KT]);
            glds16(gv + 16 * NKEY, &VTlds[cur ^ 1][(h * 32 + 16) * KT]);
        }

        int rem = nk - t * KT;  // valid keys in this tile (may exceed KT; mask below)

        // ---- QK^T: C[key][seed] = K @ Q^T
        s16x8 ka[2];
#pragma unroll
        for (int m = 0; m < 2; m++)
            ka[m] = *(const s16x8*)&Klds[cur][(m * 16 + fr) * 256 + (((h * 4 + g) ^ (fr & 7)) << 3)];
        f32x4 sc[2][2];
#pragma unroll
        for (int m = 0; m < 2; m++)
#pragma unroll
            for (int n = 0; n < 2; n++) {
                f32x4 z = (f32x4){0.f, 0.f, 0.f, 0.f};
                sc[m][n] = __builtin_amdgcn_mfma_f32_16x16x32_bf16(ka[m], qb[n], z, 0, 0, 0);
            }

        // ---- exp + mask + denom + P store (per-wave private Plds[h])
#pragma unroll
        for (int m = 0; m < 2; m++) {
            int kbase = m * 16 + g * 4;
            int col = (((kbase >> 3) ^ (fr & 3)) << 3) + (kbase & 7);
#pragma unroll
            for (int n = 0; n < 2; n++) {
                u16x4 pv;
#pragma unroll
                for (int q = 0; q < 4; q++) {
                    float e = (kbase + q < rem) ? __expf(sc[m][n][q] * SCALE) : 0.f;
                    dsum[n] += e;
                    pv[q] = f2bf(e);
                }
                *(u16x4*)&Plds[h][n * 16 + fr][col] = pv;
            }
        }
        // same-wave LDS RAW: compiler inserts lgkmcnt wait

        // ---- PV: numer[seed][dh] += P @ (V^T)^T
        s16x8 pa[2], vb[2];
        int rcol = (g ^ (fr & 3)) << 3;
#pragma unroll
        for (int m = 0; m < 2; m++)
            pa[m] = *(const s16x8*)&Plds[h][m * 16 + fr][rcol];
#pragma unroll
        for (int n = 0; n < 2; n++)
            vb[n] = *(const s16x8*)&VTlds[cur][(h * 32 + n * 16 + fr) * KT + k8];
#pragma unroll
        for (int m = 0; m < 2; m++)
#pragma unroll
            for (int n = 0; n < 2; n++)
                accp[m][n] = __builtin_amdgcn_mfma_f32_16x16x32_bf16(pa[m], vb[n], accp[m][n], 0, 0, 0);
        __syncthreads();  // drains this iter's prefetch; cur buffers fully consumed
    }

    // ---- denom: sum across the 4 lane-groups (keys were split over g and regs)
    dsum[0] += __shfl_xor(dsum[0], 16);
    dsum[0] += __shfl_xor(dsum[0], 32);
    dsum[1] += __shfl_xor(dsum[1], 16);
    dsum[1] += __shfl_xor(dsum[1], 32);

    // ---- write partials: numer layout [seed][256 dh] bf16, denom [h*32+s] f32
    char* pb = partials + ((size_t)b * NCHUNK + chunk) * PART_BYTES;
    u16* pnum = (u16*)pb;
    float* pden = (float*)(pb + 16384);
#pragma unroll
    for (int m = 0; m < 2; m++)
#pragma unroll
        for (int n = 0; n < 2; n++)
#pragma unroll
            for (int q = 0; q < 4; q++)
                pnum[(size_t)(m * 16 + g * 4 + q) * DIM + h * DHEAD + n * 16 + fr] =
                    f2bf(accp[m][n][q]);
    if (lane < 16) {
        pden[h * 32 + fr] = dsum[0];
        pden[h * 32 + 16 + fr] = dsum[1];
    }
}

// ---------------- Kernel 4: reduce partials -> O_pre = Q + numer/denom ----------------
__global__ __launch_bounds__(256) void reduce_kernel(const char* __restrict__ partials,
                                                     const float* __restrict__ qf,
                                                     const int* __restrict__ lens,
                                                     float* __restrict__ opre,
                                                     float* __restrict__ outlen) {
    int b = blockIdx.x;
    int p = threadIdx.x;
    int h = p >> 5, s = p & 31;
    float denom = 0.f;
    float num[DHEAD];
#pragma unroll
    for (int j = 0; j < DHEAD; j++) num[j] = 0.f;
    for (int c = 0; c < NCHUNK; c++) {
        const char* pb = partials + ((size_t)b * NCHUNK + c) * PART_BYTES;
        denom += ((const float*)(pb + 16384))[p];
        const u16* pn = (const u16*)pb;
#pragma unroll
        for (int j = 0; j < DHEAD; j += 8) {
            u16x8 u = *(const u16x8*)&pn[(size_t)s * DIM + h * DHEAD + j];
#pragma unroll
            for (int t = 0; t < 8; t++) num[j + t] += bf2f(u[t]);
        }
    }
    float inv = 1.f / (denom + 1e-15f);
    size_t obase = ((size_t)b * SEEDS + s) * DIM + h * DHEAD;
#pragma unroll
    for (int j = 0; j < DHEAD; j++) {
        opre[obase + j] = qf[s * DIM + h * DHEAD + j] + num[j] * inv;
    }
    if (p == 0) outlen[b] = (float)min(SEEDS, get_len(lens, b));
}

// ---------------- Kernel 5: epilogue  out = (O + relu(O @ Wo^T)) * row_mask ----------------
__global__ __launch_bounds__(256) void epilogue_kernel(const float* __restrict__ opre,
                                                       const float* __restrict__ Wo,
                                                       const int* __restrict__ lens,
                                                       float* __restrict__ out) {
    int s = blockIdx.x, b = blockIdx.y;
    int d = threadIdx.x;
    size_t rbase = ((size_t)b * SEEDS + s) * DIM;
    if (s >= get_len(lens, b)) {
        out[rbase + d] = 0.f;
        return;
    }
    __shared__ float orow[DIM];
    orow[d] = opre[rbase + d];
    __syncthreads();
    const float* wrow = Wo + (size_t)d * DIM;
    float acc = 0.f;
#pragma unroll 4
    for (int e = 0; e < DIM; e += 4) {
        f32x4 w = *(const f32x4*)(wrow + e);
        acc += orow[e] * w[0] + orow[e + 1] * w[1] + orow[e + 2] * w[2] + orow[e + 3] * w[3];
    }
    out[rbase + d] = orow[d] + fmaxf(acc, 0.f);
}

extern "C" void kernel_launch(void* const* d_in, const int* in_sizes, int n_in,
                              void* d_out, int out_size, void* d_ws, size_t ws_size,
                              hipStream_t stream) {
    const float* x  = (const float*)d_in[0];
    const int* lens = (const int*)d_in[1];
    const float* S  = (const float*)d_in[2];
    const float* Wq = (const float*)d_in[3];
    const float* Wk = (const float*)d_in[4];
    const float* Wv = (const float*)d_in[5];
    const float* Wo = (const float*)d_in[6];
    float* out = (float*)d_out;

    char* ws = (char*)d_ws;
    float* qf       = (float*)ws;                         // 32 KB
    float* opre     = (float*)(ws + 0x8000);              // 1 MB
    u16*   wb       = (u16*)  (ws + 0x108000);            // 256 KB bf16 [Wk;Wv]
    u16*   xb       = (u16*)  (ws + 0x148000);            // 32 MiB bf16 x
    char*  partials = (char*) (ws + 0x148000);            // 8.9 MB, aliases xb (disjoint in time)
    u16*   kg       = (u16*)  (ws + 0x2148000);           // 32 MiB bf16 K (col-swizzled)
    u16*   vt       = (u16*)  (ws + 0x4148000);           // 32 MiB bf16 V^T [b][dh][key]

    cvt_kernel<<<dim3(CVTBLK + SEEDS), 256, 0, stream>>>(x, Wk, Wv, S, Wq, xb, wb, qf);
    kv_gemm_kernel<<<dim3(2048), 256, 0, stream>>>(xb, wb, kg, vt);
    attn_kernel<<<dim3(NCHUNK, BATCH), 512, 0, stream>>>(kg, vt, qf, lens, partials);
    reduce_kernel<<<dim3(BATCH), 256, 0, stream>>>(partials, qf, lens, opre,
                                                   out + (size_t)BATCH * SEEDS * DIM);
    epilogue_kernel<<<dim3(SEEDS, BATCH), 256, 0, stream>>>(opre, Wo, lens, out);
}